// Round 3
// baseline (1840.815 us; speedup 1.0000x reference)
//
#include <hip/hip_runtime.h>
#include <math.h>

#define N_CELL 400000
#define N_NET  100000
#define E_PIN  1600000
#define E2     400000

// ================= CSR build =================

__global__ void __launch_bounds__(256) k_hist(
    const int* __restrict__ src, const int* __restrict__ dst,
    int* __restrict__ cell_deg, int* __restrict__ net_deg)
{
    int e = blockIdx.x * 256 + threadIdx.x;
    if (e >= E_PIN) return;
    atomicAdd(&net_deg[dst[e]], 1);
    atomicAdd(&cell_deg[src[e]], 1);
}

// segment allocation: ptr[i] = running total (order across blocks irrelevant —
// each node just needs its own contiguous range)
__global__ void __launch_bounds__(256) k_alloc(
    const int* __restrict__ deg, int* __restrict__ ptr, int* __restrict__ cur,
    int* __restrict__ cursor, int n)
{
    __shared__ int s[256];
    __shared__ int base;
    int tid = threadIdx.x;
    int i = blockIdx.x * 256 + tid;
    int d = (i < n) ? deg[i] : 0;
    int v = d;
    s[tid] = v;
    __syncthreads();
    for (int o = 1; o < 256; o <<= 1) {   // Hillis-Steele inclusive scan
        int t = (tid >= o) ? s[tid - o] : 0;
        __syncthreads();
        v += t;
        s[tid] = v;
        __syncthreads();
    }
    if (tid == 255) base = atomicAdd(cursor, v);   // v = block total
    __syncthreads();
    if (i < n) {
        int p = base + v - d;    // exclusive prefix
        ptr[i] = p;
        cur[i] = p;
    }
}

__global__ void __launch_bounds__(256) k_fill(
    const int* __restrict__ src, const int* __restrict__ dst,
    int* __restrict__ net_cur, int* __restrict__ cell_cur,
    int* __restrict__ csr_net_cell, int* __restrict__ csr_cell_eid)
{
    int e = blockIdx.x * 256 + threadIdx.x;
    if (e >= E_PIN) return;
    int s = src[e], d = dst[e];
    int p = atomicAdd(&net_cur[d], 1);
    csr_net_cell[p] = s;
    int q = atomicAdd(&cell_cur[s], 1);
    csr_cell_eid[q] = e;
}

// ============ fused gather (mean+max) + 24x64 node MLP ============
// one wave per node; 64 lanes = 8 edges x 8 dims per gather iter.
// MODE 0: net rows, gather cell_feat via csr (direct cell index)
// MODE 1: cell rows, gather net_feat via csr eid -> pins_dst[eid]
template <int MODE>
__global__ void __launch_bounds__(256) k_node(
    const float* __restrict__ self_feat, const float* __restrict__ other_feat,
    const int* __restrict__ ptr, const int* __restrict__ deg_a,
    const int* __restrict__ csr, const int* __restrict__ pins_dst,
    const float* __restrict__ W, const float* __restrict__ b,
    float* __restrict__ out)
{
    __shared__ float Ws[24 * 64];
    __shared__ float bs[64];
    __shared__ float xs[4][24];
    int tid = threadIdx.x;
    for (int i = tid; i < 24 * 64; i += 256) Ws[i] = W[i];
    if (tid < 64) bs[tid] = b[tid];
    int w = tid >> 6, l = tid & 63;
    int row = blockIdx.x * 4 + w;            // grid sized so row always valid
    int base = ptr[row], deg = deg_a[row];
    int g = l >> 3, k = l & 7;
    float sum = 0.0f, mx = -INFINITY;
    for (int j = g; j < deg; j += 8) {
        int idx = csr[base + j];
        if (MODE == 1) idx = pins_dst[idx];
        float v = other_feat[idx * 8 + k];
        sum += v;
        mx = fmaxf(mx, v);
    }
    #pragma unroll
    for (int o = 8; o < 64; o <<= 1) {       // reduce across the 8 edge-groups
        sum += __shfl_xor(sum, o);
        mx = fmaxf(mx, __shfl_xor(mx, o));
    }
    if (l < 8) {
        xs[w][k] = self_feat[row * 8 + k];
        xs[w][8 + k] = sum * (deg > 0 ? 1.0f / (float)deg : 1.0f);
        xs[w][16 + k] = (deg > 0) ? mx : 0.0f;
    }
    __syncthreads();
    float acc = bs[l];
    #pragma unroll
    for (int kk = 0; kk < 24; ++kk) acc += xs[w][kk] * Ws[kk * 64 + l];
    out[row * 64 + l] = tanhf(acc);
}

// ============ per-pin edge weight: ew = tanh(tanh(p@Wp+bp)@We+be) ============
__global__ void __launch_bounds__(256) k_ew(
    const float* __restrict__ pin_feat,
    const float* __restrict__ W_pin, const float* __restrict__ b_pin,
    const float* __restrict__ W_ew, const float* __restrict__ b_ew,
    float* __restrict__ ew)
{
    __shared__ float Wp[8 * 16];
    __shared__ float bp[16];
    __shared__ float We[16];
    __shared__ float be_s;
    int tid = threadIdx.x;
    if (tid < 128) Wp[tid] = W_pin[tid];
    if (tid < 16) { bp[tid] = b_pin[tid]; We[tid] = W_ew[tid]; }
    if (tid == 0) be_s = b_ew[0];
    __syncthreads();
    int e = blockIdx.x * 256 + tid;
    if (e >= E_PIN) return;
    float p[8];
    #pragma unroll
    for (int k = 0; k < 8; ++k) p[k] = pin_feat[e * 8 + k];
    float acc = be_s;
    #pragma unroll
    for (int j = 0; j < 16; ++j) {
        float h = bp[j];
        #pragma unroll
        for (int k = 0; k < 8; ++k) h += p[k] * Wp[k * 16 + j];
        acc += tanhf(h) * We[j];
    }
    ew[e] = tanhf(acc);
}

// ===== fused hidden: hc := hc@Wself + (gather mean of ew*hn)@Wneigh + b =====
__global__ void __launch_bounds__(256) k_hidden(
    float* __restrict__ hc, const float* __restrict__ hn,
    const float* __restrict__ ew,
    const int* __restrict__ ptr, const int* __restrict__ deg_a,
    const int* __restrict__ csr_eid, const int* __restrict__ pins_dst,
    const float* __restrict__ Wself, const float* __restrict__ Wneigh,
    const float* __restrict__ bsage)
{
    __shared__ float Ws[64 * 64];
    __shared__ float Wn[64 * 64];
    __shared__ float bs[64];
    __shared__ float xc[4][64];
    __shared__ float xn[4][64];
    int tid = threadIdx.x;
    for (int i = tid; i < 64 * 64; i += 256) { Ws[i] = Wself[i]; Wn[i] = Wneigh[i]; }
    if (tid < 64) bs[tid] = bsage[tid];
    int w = tid >> 6, l = tid & 63;
    int row = blockIdx.x * 4 + w;            // grid sized so row always valid
    int base = ptr[row], deg = deg_a[row];
    float accn = 0.0f;
    for (int j = 0; j < deg; ++j) {
        int eid = csr_eid[base + j];
        int net = pins_dst[eid];
        accn += ew[eid] * hn[net * 64 + l];
    }
    xc[w][l] = hc[row * 64 + l];
    xn[w][l] = accn * (deg > 0 ? 1.0f / (float)deg : 0.0f);
    __syncthreads();
    float acc = bs[l];
    #pragma unroll
    for (int k = 0; k < 64; ++k)
        acc += xc[w][k] * Ws[k * 64 + l] + xn[w][k] * Wn[k * 64 + l];
    hc[row * 64 + l] = acc;   // safe: row staged above by this block only
}

// ============ edge readout: one 64-lane wave per edge ============
__global__ void __launch_bounds__(256) k_edge(
    const float* __restrict__ hidden, const float* __restrict__ hn,
    const int* __restrict__ fa, const int* __restrict__ so, const int* __restrict__ gf,
    const int* __restrict__ fsn, const int* __restrict__ gfn,
    const float* __restrict__ W_dis, const float* __restrict__ b_dis,
    const float* __restrict__ W_def, const float* __restrict__ b_def,
    const float* __restrict__ cell_size, float* __restrict__ out)
{
    int e = blockIdx.x * 4 + (threadIdx.x >> 6);
    int l = threadIdx.x & 63;
    if (e >= E2) return;
    int f = fa[e], s = so[e], g = gf[e], nf = fsn[e], ng = gfn[e];
    float hf = hidden[f * 64 + l];
    float hs = hidden[s * 64 + l];
    float hg = hidden[g * 64 + l];
    float vnf = hn[nf * 64 + l];
    float vng = hn[ng * 64 + l];
    float dis = hf * W_dis[l] + hs * W_dis[64 + l] + vnf * W_dis[128 + l];
    float de  = hg * W_def[l] + hf * W_def[64 + l] + hs * W_def[128 + l]
              + vng * W_def[192 + l] + vnf * W_def[256 + l];
    #pragma unroll
    for (int o = 32; o > 0; o >>= 1) {
        dis += __shfl_down(dis, o);
        de  += __shfl_down(de, o);
    }
    if (l == 0) {
        float d1 = expf(-2.0f + 15.0f * tanhf(dis + b_dis[0]));
        float d2 = tanhf(de + b_def[0]) * 6.28318530717958647692f;
        float bx = (cell_size[f * 2 + 0] + cell_size[s * 2 + 0]) * 0.5f;
        float by = (cell_size[f * 2 + 1] + cell_size[s * 2 + 1]) * 0.5f;
        out[e] = d1 + fminf(bx, by);
        out[E2 + e] = d2;
    }
}

extern "C" void kernel_launch(void* const* d_in, const int* in_sizes, int n_in,
                              void* d_out, int out_size, void* d_ws, size_t ws_size,
                              hipStream_t stream)
{
    const float* cell_feat = (const float*)d_in[0];
    const float* net_feat  = (const float*)d_in[1];
    const float* pin_feat  = (const float*)d_in[2];
    const float* cell_size = (const float*)d_in[3];
    const float* W_cell = (const float*)d_in[4];
    const float* b_cell = (const float*)d_in[5];
    const float* W_net  = (const float*)d_in[6];
    const float* b_net  = (const float*)d_in[7];
    const float* W_pin  = (const float*)d_in[8];
    const float* b_pin  = (const float*)d_in[9];
    const float* W_ew   = (const float*)d_in[10];
    const float* b_ew   = (const float*)d_in[11];
    const float* W_self = (const float*)d_in[12];
    const float* W_neigh= (const float*)d_in[13];
    const float* b_sage = (const float*)d_in[14];
    const float* W_dis  = (const float*)d_in[15];
    const float* b_dis  = (const float*)d_in[16];
    const float* W_def  = (const float*)d_in[17];
    const float* b_def  = (const float*)d_in[18];
    const int* pins_src = (const int*)d_in[19];
    const int* pins_dst = (const int*)d_in[20];
    const int* fathers  = (const int*)d_in[21];
    const int* sons     = (const int*)d_in[22];
    const int* grandf   = (const int*)d_in[23];
    const int* fs_nets  = (const int*)d_in[24];
    const int* gf_nets  = (const int*)d_in[25];

    // ---- workspace layout (256B aligned) ----
    char* ws = (char*)d_ws;
    size_t off = 0;
    auto alloc = [&](size_t bytes) -> void* {
        void* p = ws + off;
        off += (bytes + 255) & ~(size_t)255;
        return p;
    };
    // zeroed region: cursors + degree arrays (~2MB)
    int* cursors   = (int*)alloc(2 * 4);
    int* net_deg   = (int*)alloc((size_t)N_NET * 4);
    int* cell_deg  = (int*)alloc((size_t)N_CELL * 4);
    size_t zero_bytes = off;
    // uninitialized:
    int* net_ptr   = (int*)alloc((size_t)N_NET * 4);
    int* net_cur   = (int*)alloc((size_t)N_NET * 4);
    int* cell_ptr  = (int*)alloc((size_t)N_CELL * 4);
    int* cell_cur  = (int*)alloc((size_t)N_CELL * 4);
    int* csr_net_cell = (int*)alloc((size_t)E_PIN * 4);   // cell idx per net-slot
    int* csr_cell_eid = (int*)alloc((size_t)E_PIN * 4);   // edge id per cell-slot
    float* ew = (float*)alloc((size_t)E_PIN * 4);
    float* hc = (float*)alloc((size_t)N_CELL * 64 * 4);   // becomes hidden in place
    float* hn = (float*)alloc((size_t)N_NET * 64 * 4);
    if (off > ws_size) return;   // fail loudly (absmax), don't fault

    hipMemsetAsync(d_ws, 0, zero_bytes, stream);

    // CSR build
    k_hist<<<(E_PIN + 255) / 256, 256, 0, stream>>>(pins_src, pins_dst, cell_deg, net_deg);
    k_alloc<<<(N_NET + 255) / 256, 256, 0, stream>>>(net_deg, net_ptr, net_cur, &cursors[0], N_NET);
    k_alloc<<<(N_CELL + 255) / 256, 256, 0, stream>>>(cell_deg, cell_ptr, cell_cur, &cursors[1], N_CELL);
    k_fill<<<(E_PIN + 255) / 256, 256, 0, stream>>>(
        pins_src, pins_dst, net_cur, cell_cur, csr_net_cell, csr_cell_eid);

    // fused gather + node MLPs (grids divide exactly: 100000/4, 400000/4)
    k_node<0><<<N_NET / 4, 256, 0, stream>>>(
        net_feat, cell_feat, net_ptr, net_deg, csr_net_cell, pins_dst, W_net, b_net, hn);
    k_node<1><<<N_CELL / 4, 256, 0, stream>>>(
        cell_feat, net_feat, cell_ptr, cell_deg, csr_cell_eid, pins_dst, W_cell, b_cell, hc);

    // edge weights
    k_ew<<<(E_PIN + 255) / 256, 256, 0, stream>>>(pin_feat, W_pin, b_pin, W_ew, b_ew, ew);

    // fused SAGE hidden (gather, no atomics), in place over hc
    k_hidden<<<N_CELL / 4, 256, 0, stream>>>(
        hc, hn, ew, cell_ptr, cell_deg, csr_cell_eid, pins_dst, W_self, W_neigh, b_sage);

    // edge readouts
    k_edge<<<E2 / 4, 256, 0, stream>>>(
        hc, hn, fathers, sons, grandf, fs_nets, gf_nets,
        W_dis, b_dis, W_def, b_def, cell_size, (float*)d_out);
}

// Round 4
// 1388.798 us; speedup vs baseline: 1.3255x; 1.3255x over previous
//
#include <hip/hip_runtime.h>
#include <math.h>

#define N_CELL 400000
#define N_NET  100000
#define E_PIN  1600000
#define E2     400000

// ================= CSR build =================

__global__ void __launch_bounds__(256) k_hist(
    const int* __restrict__ src, const int* __restrict__ dst,
    int* __restrict__ cell_deg, int* __restrict__ net_deg)
{
    int e = blockIdx.x * 256 + threadIdx.x;
    if (e >= E_PIN) return;
    atomicAdd(&net_deg[dst[e]], 1);
    atomicAdd(&cell_deg[src[e]], 1);
}

__global__ void __launch_bounds__(256) k_alloc(
    const int* __restrict__ deg, int* __restrict__ ptr, int* __restrict__ cur,
    int* __restrict__ cursor, int n)
{
    __shared__ int s[256];
    __shared__ int base;
    int tid = threadIdx.x;
    int i = blockIdx.x * 256 + tid;
    int d = (i < n) ? deg[i] : 0;
    int v = d;
    s[tid] = v;
    __syncthreads();
    for (int o = 1; o < 256; o <<= 1) {
        int t = (tid >= o) ? s[tid - o] : 0;
        __syncthreads();
        v += t;
        s[tid] = v;
        __syncthreads();
    }
    if (tid == 255) base = atomicAdd(cursor, v);
    __syncthreads();
    if (i < n) {
        int p = base + v - d;
        ptr[i] = p;
        cur[i] = p;
    }
}

__global__ void __launch_bounds__(256) k_fill(
    const int* __restrict__ src, const int* __restrict__ dst,
    int* __restrict__ net_cur, int* __restrict__ cell_cur,
    int* __restrict__ csr_net_cell, int* __restrict__ csr_cell_net,
    int* __restrict__ csr_cell_eid)
{
    int e = blockIdx.x * 256 + threadIdx.x;
    if (e >= E_PIN) return;
    int s = src[e], d = dst[e];
    int p = atomicAdd(&net_cur[d], 1);
    csr_net_cell[p] = s;
    int q = atomicAdd(&cell_cur[s], 1);
    csr_cell_net[q] = d;
    csr_cell_eid[q] = e;
}

// ============ fused gather (mean+max) + 24x64 node MLP ============
// one wave per node; csr holds the gather index directly (coalesced load),
// broadcast via shfl so all feat-row loads are independent.
__global__ void __launch_bounds__(256) k_node(
    const float* __restrict__ self_feat, const float* __restrict__ other_feat,
    const int* __restrict__ ptr, const int* __restrict__ deg_a,
    const int* __restrict__ csr,
    const float* __restrict__ W, const float* __restrict__ b,
    float* __restrict__ out)
{
    __shared__ float Ws[24 * 64];
    __shared__ float bs[64];
    __shared__ float xs[4][24];
    int tid = threadIdx.x;
    for (int i = tid; i < 24 * 64; i += 256) Ws[i] = W[i];
    if (tid < 64) bs[tid] = b[tid];
    int w = tid >> 6, l = tid & 63;
    int row = blockIdx.x * 4 + w;            // grid sized so row always valid
    int base = ptr[row], deg = deg_a[row];
    int g = l >> 3, k = l & 7;
    float sum = 0.0f, mx = -INFINITY;
    for (int j0 = 0; j0 < deg; j0 += 64) {
        int j = j0 + l;
        int idx_j = (j < deg) ? csr[base + j] : 0;   // coalesced
        int lim = deg - j0; if (lim > 64) lim = 64;
        for (int t = 0; t < lim; t += 8) {
            int te = t + g;                           // edge slot for my group
            int idx = __shfl(idx_j, te);
            if (te < lim) {
                float v = other_feat[idx * 8 + k];
                sum += v;
                mx = fmaxf(mx, v);
            }
        }
    }
    #pragma unroll
    for (int o = 8; o < 64; o <<= 1) {
        sum += __shfl_xor(sum, o);
        mx = fmaxf(mx, __shfl_xor(mx, o));
    }
    if (l < 8) {
        xs[w][k] = self_feat[row * 8 + k];
        xs[w][8 + k] = sum * (deg > 0 ? 1.0f / (float)deg : 1.0f);
        xs[w][16 + k] = (deg > 0) ? mx : 0.0f;
    }
    __syncthreads();
    float acc = bs[l];
    #pragma unroll
    for (int kk = 0; kk < 24; ++kk) acc += xs[w][kk] * Ws[kk * 64 + l];
    out[row * 64 + l] = tanhf(acc);
}

// ============ per-pin edge weight: ew = tanh(tanh(p@Wp+bp)@We+be) ============
__global__ void __launch_bounds__(256) k_ew(
    const float* __restrict__ pin_feat,
    const float* __restrict__ W_pin, const float* __restrict__ b_pin,
    const float* __restrict__ W_ew, const float* __restrict__ b_ew,
    float* __restrict__ ew)
{
    __shared__ float Wp[8 * 16];
    __shared__ float bp[16];
    __shared__ float We[16];
    __shared__ float be_s;
    int tid = threadIdx.x;
    if (tid < 128) Wp[tid] = W_pin[tid];
    if (tid < 16) { bp[tid] = b_pin[tid]; We[tid] = W_ew[tid]; }
    if (tid == 0) be_s = b_ew[0];
    __syncthreads();
    int e = blockIdx.x * 256 + tid;
    if (e >= E_PIN) return;
    float p[8];
    #pragma unroll
    for (int k = 0; k < 8; ++k) p[k] = pin_feat[e * 8 + k];
    float acc = be_s;
    #pragma unroll
    for (int j = 0; j < 16; ++j) {
        float h = bp[j];
        #pragma unroll
        for (int k = 0; k < 8; ++k) h += p[k] * Wp[k * 16 + j];
        acc += tanhf(h) * We[j];
    }
    ew[e] = tanhf(acc);
}

// ===== fused hidden: hc := hc@Wself + (gather mean of ew*hn)@Wneigh + b =====
// 512 threads = 8 waves = 8 rows per block; shfl-broadcast gather.
__global__ void __launch_bounds__(512) k_hidden(
    float* __restrict__ hc, const float* __restrict__ hn,
    const float* __restrict__ ew,
    const int* __restrict__ ptr, const int* __restrict__ deg_a,
    const int* __restrict__ csr_net, const int* __restrict__ csr_eid,
    const float* __restrict__ Wself, const float* __restrict__ Wneigh,
    const float* __restrict__ bsage)
{
    __shared__ float Ws[64 * 64];
    __shared__ float Wn[64 * 64];
    __shared__ float bs[64];
    __shared__ float xc[8][64];
    __shared__ float xn[8][64];
    int tid = threadIdx.x;
    for (int i = tid; i < 64 * 64; i += 512) { Ws[i] = Wself[i]; Wn[i] = Wneigh[i]; }
    if (tid < 64) bs[tid] = bsage[tid];
    int w = tid >> 6, l = tid & 63;
    int row = blockIdx.x * 8 + w;            // grid sized so row always valid
    int base = ptr[row], deg = deg_a[row];
    float accn = 0.0f;
    for (int j0 = 0; j0 < deg; j0 += 64) {
        int j = j0 + l;
        int net_j = 0; float ew_j = 0.0f;
        if (j < deg) {
            net_j = csr_net[base + j];            // coalesced
            ew_j = ew[csr_eid[base + j]];         // one independent 4B gather
        }
        int lim = deg - j0; if (lim > 64) lim = 64;
        for (int t = 0; t < lim; ++t) {
            int net = __shfl(net_j, t);
            float wt = __shfl(ew_j, t);
            accn += wt * hn[net * 64 + l];        // independent row loads
        }
    }
    xc[w][l] = hc[row * 64 + l];
    xn[w][l] = accn * (deg > 0 ? 1.0f / (float)deg : 0.0f);
    __syncthreads();
    float acc = bs[l];
    #pragma unroll
    for (int k = 0; k < 64; ++k)
        acc += xc[w][k] * Ws[k * 64 + l] + xn[w][k] * Wn[k * 64 + l];
    hc[row * 64 + l] = acc;   // safe: row staged above by this block only
}

// ============ edge readout: one 64-lane wave per edge ============
__global__ void __launch_bounds__(256) k_edge(
    const float* __restrict__ hidden, const float* __restrict__ hn,
    const int* __restrict__ fa, const int* __restrict__ so, const int* __restrict__ gf,
    const int* __restrict__ fsn, const int* __restrict__ gfn,
    const float* __restrict__ W_dis, const float* __restrict__ b_dis,
    const float* __restrict__ W_def, const float* __restrict__ b_def,
    const float* __restrict__ cell_size, float* __restrict__ out)
{
    int e = blockIdx.x * 4 + (threadIdx.x >> 6);
    int l = threadIdx.x & 63;
    if (e >= E2) return;
    int f = fa[e], s = so[e], g = gf[e], nf = fsn[e], ng = gfn[e];
    float hf = hidden[f * 64 + l];
    float hs = hidden[s * 64 + l];
    float hg = hidden[g * 64 + l];
    float vnf = hn[nf * 64 + l];
    float vng = hn[ng * 64 + l];
    float dis = hf * W_dis[l] + hs * W_dis[64 + l] + vnf * W_dis[128 + l];
    float de  = hg * W_def[l] + hf * W_def[64 + l] + hs * W_def[128 + l]
              + vng * W_def[192 + l] + vnf * W_def[256 + l];
    #pragma unroll
    for (int o = 32; o > 0; o >>= 1) {
        dis += __shfl_down(dis, o);
        de  += __shfl_down(de, o);
    }
    if (l == 0) {
        float d1 = expf(-2.0f + 15.0f * tanhf(dis + b_dis[0]));
        float d2 = tanhf(de + b_def[0]) * 6.28318530717958647692f;
        float bx = (cell_size[f * 2 + 0] + cell_size[s * 2 + 0]) * 0.5f;
        float by = (cell_size[f * 2 + 1] + cell_size[s * 2 + 1]) * 0.5f;
        out[e] = d1 + fminf(bx, by);
        out[E2 + e] = d2;
    }
}

extern "C" void kernel_launch(void* const* d_in, const int* in_sizes, int n_in,
                              void* d_out, int out_size, void* d_ws, size_t ws_size,
                              hipStream_t stream)
{
    const float* cell_feat = (const float*)d_in[0];
    const float* net_feat  = (const float*)d_in[1];
    const float* pin_feat  = (const float*)d_in[2];
    const float* cell_size = (const float*)d_in[3];
    const float* W_cell = (const float*)d_in[4];
    const float* b_cell = (const float*)d_in[5];
    const float* W_net  = (const float*)d_in[6];
    const float* b_net  = (const float*)d_in[7];
    const float* W_pin  = (const float*)d_in[8];
    const float* b_pin  = (const float*)d_in[9];
    const float* W_ew   = (const float*)d_in[10];
    const float* b_ew   = (const float*)d_in[11];
    const float* W_self = (const float*)d_in[12];
    const float* W_neigh= (const float*)d_in[13];
    const float* b_sage = (const float*)d_in[14];
    const float* W_dis  = (const float*)d_in[15];
    const float* b_dis  = (const float*)d_in[16];
    const float* W_def  = (const float*)d_in[17];
    const float* b_def  = (const float*)d_in[18];
    const int* pins_src = (const int*)d_in[19];
    const int* pins_dst = (const int*)d_in[20];
    const int* fathers  = (const int*)d_in[21];
    const int* sons     = (const int*)d_in[22];
    const int* grandf   = (const int*)d_in[23];
    const int* fs_nets  = (const int*)d_in[24];
    const int* gf_nets  = (const int*)d_in[25];

    // ---- workspace layout (256B aligned) ----
    char* ws = (char*)d_ws;
    size_t off = 0;
    auto alloc = [&](size_t bytes) -> void* {
        void* p = ws + off;
        off += (bytes + 255) & ~(size_t)255;
        return p;
    };
    int* cursors   = (int*)alloc(2 * 4);
    int* net_deg   = (int*)alloc((size_t)N_NET * 4);
    int* cell_deg  = (int*)alloc((size_t)N_CELL * 4);
    size_t zero_bytes = off;
    int* net_ptr   = (int*)alloc((size_t)N_NET * 4);
    int* net_cur   = (int*)alloc((size_t)N_NET * 4);
    int* cell_ptr  = (int*)alloc((size_t)N_CELL * 4);
    int* cell_cur  = (int*)alloc((size_t)N_CELL * 4);
    int* csr_net_cell = (int*)alloc((size_t)E_PIN * 4);   // cell idx per net-slot
    int* csr_cell_net = (int*)alloc((size_t)E_PIN * 4);   // net idx per cell-slot
    int* csr_cell_eid = (int*)alloc((size_t)E_PIN * 4);   // edge id per cell-slot
    float* ew = (float*)alloc((size_t)E_PIN * 4);
    float* hc = (float*)alloc((size_t)N_CELL * 64 * 4);   // becomes hidden in place
    float* hn = (float*)alloc((size_t)N_NET * 64 * 4);
    if (off > ws_size) return;   // fail loudly (absmax), don't fault

    hipMemsetAsync(d_ws, 0, zero_bytes, stream);

    // CSR build
    k_hist<<<(E_PIN + 255) / 256, 256, 0, stream>>>(pins_src, pins_dst, cell_deg, net_deg);
    k_alloc<<<(N_NET + 255) / 256, 256, 0, stream>>>(net_deg, net_ptr, net_cur, &cursors[0], N_NET);
    k_alloc<<<(N_CELL + 255) / 256, 256, 0, stream>>>(cell_deg, cell_ptr, cell_cur, &cursors[1], N_CELL);
    k_fill<<<(E_PIN + 255) / 256, 256, 0, stream>>>(
        pins_src, pins_dst, net_cur, cell_cur, csr_net_cell, csr_cell_net, csr_cell_eid);

    // fused gather + node MLPs
    k_node<<<N_NET / 4, 256, 0, stream>>>(
        net_feat, cell_feat, net_ptr, net_deg, csr_net_cell, W_net, b_net, hn);
    k_node<<<N_CELL / 4, 256, 0, stream>>>(
        cell_feat, net_feat, cell_ptr, cell_deg, csr_cell_net, W_cell, b_cell, hc);

    // edge weights
    k_ew<<<(E_PIN + 255) / 256, 256, 0, stream>>>(pin_feat, W_pin, b_pin, W_ew, b_ew, ew);

    // fused SAGE hidden (gather, no atomics), in place over hc
    k_hidden<<<N_CELL / 8, 512, 0, stream>>>(
        hc, hn, ew, cell_ptr, cell_deg, csr_cell_net, csr_cell_eid, W_self, W_neigh, b_sage);

    // edge readouts
    k_edge<<<E2 / 4, 256, 0, stream>>>(
        hc, hn, fathers, sons, grandf, fs_nets, gf_nets,
        W_dis, b_dis, W_def, b_def, cell_size, (float*)d_out);
}